// Round 5
// baseline (11848.421 us; speedup 1.0000x reference)
//
#include <hip/hip_runtime.h>
#include <math.h>

typedef float f4 __attribute__((ext_vector_type(4)));
typedef _Float16 h8 __attribute__((ext_vector_type(8)));

// ---------------- workspace layout (float offsets) ----------------
// AX     : A@x all t [i][t*128+b*2+c]       6,144,000
// AH0h/l : A@H0new split f16 [1024][4096]   2 x 2,097,152
// AH1h/l : A@H1prev split f16 [1024][4096]  2 x 2,097,152
// H1F    : H1 fp32 [1000*64][64]            4,096,000
// C0,C1  : cell state fp32                  2 x 4,096,000
// HTh/HTl: H^T split f16 [4096][1024]       2 x 2,097,152
// Ah/Al  : split f16 A [1024][1024]         2 x 524,288
// W0h/l  : Wh0 split f16 [256][64]          2 x 8,192
// W1h/l  : [Wx1|Wh1] split f16 [256][128]   2 x 16,384
// aliases: At fp32 [1000][1000] in C0 region (dead before C0 zeroed);
//          Xr (6,144,000) in AH0h.. region (dead before AH zeroed);
//          H0F fp32 [1000][4096] in AH1h/l region (dead before gemm_ah #2).
#define WS_AX     0
#define WS_AH0H   6144000
#define WS_AH0L   8241152
#define WS_AH1H   10338304
#define WS_AH1L   12435456
#define WS_H1F    14532608
#define WS_C0     18628608
#define WS_C1     22724608
#define WS_HTH    26820608
#define WS_HTL    28917760
#define WS_AH16   31014912
#define WS_AL16   31539200
#define WS_W0H    32063488
#define WS_W0L    32071680
#define WS_W1H    32079872
#define WS_W1L    32096256
// end = 32,112,640 floats = 128.45 MB (same footprint as R4, which ran)

// ---------------- A = softmax(relu(E1 @ E2^T)) in fp64, store A^T ----------------
__global__ __launch_bounds__(256) void compute_A(const float* __restrict__ E1,
                                                 const float* __restrict__ E2,
                                                 float* __restrict__ At)
{
    __shared__ double z[1000];
    __shared__ double red[256];
    __shared__ double e1[16];
    const int i = blockIdx.x;
    const int tid = threadIdx.x;
    if (tid < 16) e1[tid] = (double)E1[i * 16 + tid];
    __syncthreads();
    double lmax = -1e300;
    for (int j = tid; j < 1000; j += 256) {
        double s = 0.0;
        #pragma unroll
        for (int c = 0; c < 16; ++c) s += e1[c] * (double)E2[j * 16 + c];
        if (s < 0.0) s = 0.0;
        z[j] = s;
        if (s > lmax) lmax = s;
    }
    red[tid] = lmax; __syncthreads();
    for (int off = 128; off > 0; off >>= 1) {
        if (tid < off) red[tid] = fmax(red[tid], red[tid + off]);
        __syncthreads();
    }
    const double zmax = red[0];
    __syncthreads();
    double lsum = 0.0;
    for (int j = tid; j < 1000; j += 256) {
        double e = exp(z[j] - zmax);
        z[j] = e;
        lsum += e;
    }
    red[tid] = lsum; __syncthreads();
    for (int off = 128; off > 0; off >>= 1) {
        if (tid < off) red[tid] += red[tid + off];
        __syncthreads();
    }
    const double inv = 1.0 / red[0];
    for (int j = tid; j < 1000; j += 256)
        At[(size_t)j * 1000 + i] = (float)(z[j] * inv);
}

// ---------------- x [B,T,N,C] -> Xr [j][t*128 + b*2 + c] ----------------
__global__ __launch_bounds__(256) void transpose_x(const float* __restrict__ x,
                                                   float* __restrict__ Xr)
{
    int o = blockIdx.x * 256 + threadIdx.x;
    if (o >= 6144000) return;
    int j = o / 6144;
    int r = o - j * 6144;
    int t = r >> 7;
    int q = r & 127;
    int b = q >> 1;
    int c = q & 1;
    Xr[o] = x[(((size_t)(b * 48 + t)) * 1000 + j) * 2 + c];
}

__global__ __launch_bounds__(256) void zero_kernel(float* __restrict__ p, int n4)
{
    int i = blockIdx.x * 256 + threadIdx.x;
    if (i < n4) { f4 z = {0.f, 0.f, 0.f, 0.f}; ((f4*)p)[i] = z; }
}

// ---------------- weight split-f16 prep (once) ----------------
__global__ __launch_bounds__(256) void prep_w2(const float* __restrict__ Wh0,
                                               const float* __restrict__ Wx1,
                                               const float* __restrict__ Wh1,
                                               _Float16* __restrict__ W0h,
                                               _Float16* __restrict__ W0l,
                                               _Float16* __restrict__ W1h,
                                               _Float16* __restrict__ W1l)
{
    int idx = blockIdx.x * 256 + threadIdx.x;
    if (idx < 16384) {                    // [256][64] = torch layout of Wh0
        float v = Wh0[idx];
        _Float16 hi = (_Float16)v;
        W0h[idx] = hi;
        W0l[idx] = (_Float16)((v - (float)hi) * 2048.f);
    }
    int j = idx - 16384;
    if (j >= 0 && j < 32768) {            // [256][128]: k<64 -> Wx1, k>=64 -> Wh1
        int gc = j >> 7, k = j & 127;
        float v = (k < 64) ? Wx1[gc * 64 + k] : Wh1[gc * 64 + (k - 64)];
        _Float16 hi = (_Float16)v;
        W1h[j] = hi;
        W1l[j] = (_Float16)((v - (float)hi) * 2048.f);
    }
}

// ---------------- split A^T fp32 -> Ah/Al f16 [m=1024][k=1024] ----------------
__global__ __launch_bounds__(256) void prep_A(const float* __restrict__ At,
                                              _Float16* __restrict__ Ahh,
                                              _Float16* __restrict__ All)
{
    int idx = blockIdx.x * 256 + threadIdx.x;   // 1,048,576
    int m = idx >> 10, k = idx & 1023;
    float v = (m < 1000 && k < 1000) ? At[(size_t)k * 1000 + m] : 0.f;
    _Float16 hi = (_Float16)v;
    Ahh[idx] = hi;
    All[idx] = (_Float16)((v - (float)hi) * 2048.f);
}

// ---------------- fp32 GEMM (used once for AX) ----------------
__global__ __launch_bounds__(256) void gemm1000(const float* __restrict__ At,
                                                const float* __restrict__ B,
                                                float* __restrict__ C,
                                                int ncols)
{
    __shared__ float As[8][64];
    __shared__ float Bs[8][128];
    const int tid = threadIdx.x;
    const int tx = tid & 15;
    const int ty = tid >> 4;
    const int row0 = blockIdx.x * 64;
    const int col0 = blockIdx.y * 128;
    const int lm = tid & 63;
    const int lk = tid >> 6;
    const int bcol = tid & 127;
    const int bk = tid >> 7;
    const bool arow_ok = (row0 + lm) < 1000;

    float acc[4][8];
    #pragma unroll
    for (int r = 0; r < 4; ++r)
        #pragma unroll
        for (int c = 0; c < 8; ++c) acc[r][c] = 0.f;

    for (int k0 = 0; k0 < 1000; k0 += 8) {
        float a0 = arow_ok ? At[(size_t)(k0 + lk) * 1000 + row0 + lm] : 0.f;
        float a1 = arow_ok ? At[(size_t)(k0 + lk + 4) * 1000 + row0 + lm] : 0.f;
        float bv[4];
        #pragma unroll
        for (int kk = 0; kk < 4; ++kk)
            bv[kk] = B[(size_t)(k0 + bk * 4 + kk) * ncols + col0 + bcol];
        __syncthreads();
        As[lk][lm] = a0;
        As[lk + 4][lm] = a1;
        #pragma unroll
        for (int kk = 0; kk < 4; ++kk) Bs[bk * 4 + kk][bcol] = bv[kk];
        __syncthreads();
        #pragma unroll
        for (int k = 0; k < 8; ++k) {
            f4 av = *(const f4*)&As[k][ty * 4];
            f4 b0 = *(const f4*)&Bs[k][tx * 8];
            f4 b1 = *(const f4*)&Bs[k][tx * 8 + 4];
            #pragma unroll
            for (int r = 0; r < 4; ++r) {
                float a = av[r];
                acc[r][0] = fmaf(a, b0[0], acc[r][0]);
                acc[r][1] = fmaf(a, b0[1], acc[r][1]);
                acc[r][2] = fmaf(a, b0[2], acc[r][2]);
                acc[r][3] = fmaf(a, b0[3], acc[r][3]);
                acc[r][4] = fmaf(a, b1[0], acc[r][4]);
                acc[r][5] = fmaf(a, b1[1], acc[r][5]);
                acc[r][6] = fmaf(a, b1[2], acc[r][6]);
                acc[r][7] = fmaf(a, b1[3], acc[r][7]);
            }
        }
    }
    #pragma unroll
    for (int r = 0; r < 4; ++r) {
        int row = row0 + ty * 4 + r;
        if (row < 1000) {
            f4 o0 = {acc[r][0], acc[r][1], acc[r][2], acc[r][3]};
            f4 o1 = {acc[r][4], acc[r][5], acc[r][6], acc[r][7]};
            *(f4*)&C[(size_t)row * ncols + col0 + tx * 8]     = o0;
            *(f4*)&C[(size_t)row * ncols + col0 + tx * 8 + 4] = o1;
        }
    }
}

// ---------------- H fp32 [1000 nodes][4096] -> HT split f16 [4096][1024] ----------------
__global__ __launch_bounds__(256) void transpose_split(const float* __restrict__ H,
                                                       _Float16* __restrict__ HTh,
                                                       _Float16* __restrict__ HTl)
{
    __shared__ float tile[32][33];
    const int tid = threadIdx.x;
    const int tx = tid & 31;
    const int ty = tid >> 5;            // 0..7
    const int n0 = blockIdx.x * 32;     // 128 n-tiles
    const int k0 = blockIdx.y * 32;     // 32 k-tiles
    #pragma unroll
    for (int j = 0; j < 4; ++j) {
        int k = k0 + ty * 4 + j;
        tile[ty * 4 + j][tx] = (k < 1000) ? H[(size_t)k * 4096 + n0 + tx] : 0.f;
    }
    __syncthreads();
    #pragma unroll
    for (int j = 0; j < 4; ++j) {
        int n = n0 + ty * 4 + j;
        float v = tile[tx][ty * 4 + j];
        _Float16 hi = (_Float16)v;
        size_t o = (size_t)n * 1024 + k0 + tx;
        HTh[o] = hi;
        HTl[o] = (_Float16)((v - (float)hi) * 2048.f);
    }
}

// ---------------- MFMA split-f16 GEMM: AH = A @ HT^T, split-f16 output ----------------
// A [1024][1024] f16 (hi,lo), HT [4096][1024] f16 (hi,lo) -- both row-major-by-K.
// BM=128 BN=128 BK=32; 256 thr = 4 waves 2x2; wave tile 64x64 = 4x4 frags 16x16x32.
__global__ __launch_bounds__(256) void gemm_ah(
    const _Float16* __restrict__ Ahg, const _Float16* __restrict__ Alg,
    const _Float16* __restrict__ Bhg, const _Float16* __restrict__ Blg,
    _Float16* __restrict__ Ch, _Float16* __restrict__ Cl)
{
    __shared__ __align__(16) _Float16 Ahs[128 * 40];
    __shared__ __align__(16) _Float16 Als[128 * 40];
    __shared__ __align__(16) _Float16 Bhs[128 * 40];
    __shared__ __align__(16) _Float16 Bls[128 * 40];
    const int tid = threadIdx.x;
    const int lane = tid & 63;
    const int w = tid >> 6;
    const int wr = w >> 1, wc = w & 1;
    const int g = lane >> 4, l15 = lane & 15;
    const int m0 = blockIdx.x * 128, n0 = blockIdx.y * 128;
    const int srow = tid >> 2;          // 0..63
    const int scol = (tid & 3) * 8;     // f16 col 0,8,16,24

    f4 acc0[4][4], acc1[4][4];
    #pragma unroll
    for (int a = 0; a < 4; ++a)
        #pragma unroll
        for (int b = 0; b < 4; ++b) {
            acc0[a][b] = (f4){0.f, 0.f, 0.f, 0.f};
            acc1[a][b] = (f4){0.f, 0.f, 0.f, 0.f};
        }

    for (int ks = 0; ks < 32; ++ks) {
        const int kb = ks * 32 + scol;
        f4 va[2], vl[2], vbh[2], vbl[2];
        #pragma unroll
        for (int s = 0; s < 2; ++s) {
            const size_t ga = (size_t)(m0 + s * 64 + srow) * 1024 + kb;
            const size_t gb = (size_t)(n0 + s * 64 + srow) * 1024 + kb;
            va[s]  = *(const f4*)&Ahg[ga];
            vl[s]  = *(const f4*)&Alg[ga];
            vbh[s] = *(const f4*)&Bhg[gb];
            vbl[s] = *(const f4*)&Blg[gb];
        }
        __syncthreads();
        #pragma unroll
        for (int s = 0; s < 2; ++s) {
            const int lo = (s * 64 + srow) * 40 + scol;
            *(f4*)&Ahs[lo] = va[s];
            *(f4*)&Als[lo] = vl[s];
            *(f4*)&Bhs[lo] = vbh[s];
            *(f4*)&Bls[lo] = vbl[s];
        }
        __syncthreads();

        h8 fa[4], fl[4];
        #pragma unroll
        for (int mf = 0; mf < 4; ++mf) {
            const int ao = (wr * 64 + mf * 16 + l15) * 40 + g * 8;
            fa[mf] = *(const h8*)&Ahs[ao];
            fl[mf] = *(const h8*)&Als[ao];
        }
        #pragma unroll
        for (int nf = 0; nf < 4; ++nf) {
            const int bo = (wc * 64 + nf * 16 + l15) * 40 + g * 8;
            const h8 bh = *(const h8*)&Bhs[bo];
            const h8 bl = *(const h8*)&Bls[bo];
            #pragma unroll
            for (int mf = 0; mf < 4; ++mf) {
                acc0[mf][nf] = __builtin_amdgcn_mfma_f32_16x16x32_f16(fa[mf], bh, acc0[mf][nf], 0, 0, 0);
                acc1[mf][nf] = __builtin_amdgcn_mfma_f32_16x16x32_f16(fa[mf], bl, acc1[mf][nf], 0, 0, 0);
                acc1[mf][nf] = __builtin_amdgcn_mfma_f32_16x16x32_f16(fl[mf], bh, acc1[mf][nf], 0, 0, 0);
            }
        }
    }

    // C/D layout (m89-verified): col = lane&15, row = (lane>>4)*4 + e; split-f16 out
    #pragma unroll
    for (int mf = 0; mf < 4; ++mf)
        #pragma unroll
        for (int nf = 0; nf < 4; ++nf) {
            const int row = m0 + wr * 64 + mf * 16 + g * 4;
            const int col = n0 + wc * 64 + nf * 16 + l15;
            #pragma unroll
            for (int e = 0; e < 4; ++e) {
                float v = acc0[mf][nf][e] + acc1[mf][nf][e] * (1.f / 2048.f);
                _Float16 hi = (_Float16)v;
                size_t o = (size_t)(row + e) * 4096 + col;
                Ch[o] = hi;
                Cl[o] = (_Float16)((v - (float)hi) * 2048.f);
            }
        }
}

// ---------------- MFMA gate GEMM + fused LSTM pointwise ----------------
// gates[r][gc] = sum_k AH[r][k] * W[gc][k] (split-f16 3-pass) + biases (+ x-path)
// Block = node i (64 rows r=i*64+b), 256 gc. 4 waves by h-group; no LDS, frags from L2.
// A-frag: row=l15 (b=mf*16+l15), k=(lane>>4)*8+j. B-frag: col=l15 (gc), same k.
__global__ __launch_bounds__(256) void gates_mfma(
    const _Float16* __restrict__ A0h, const _Float16* __restrict__ A0l,  // k 0..63
    const _Float16* __restrict__ A1h, const _Float16* __restrict__ A1l,  // k 64..127 (null -> K=64)
    const _Float16* __restrict__ Wgh, const _Float16* __restrict__ Wgl,  // [256][K]
    const float* __restrict__ b1, const float* __restrict__ b2,
    const float* __restrict__ AX, const float* __restrict__ WxE, int t,
    float* __restrict__ Cst, float* __restrict__ Hout)
{
    const int tid = threadIdx.x;
    const int lane = tid & 63;
    const int w = tid >> 6;             // h-group 0..3
    const int lg = lane >> 4, l15 = lane & 15;
    const int i = blockIdx.x;
    const int K = A1h ? 128 : 64;
    const int h = w * 16 + l15;

    f4 acc0[4][4], acc1[4][4];          // [mf][gate]
    #pragma unroll
    for (int a = 0; a < 4; ++a)
        #pragma unroll
        for (int b = 0; b < 4; ++b) {
            acc0[a][b] = (f4){0.f, 0.f, 0.f, 0.f};
            acc1[a][b] = (f4){0.f, 0.f, 0.f, 0.f};
        }

    const int nks = K >> 5;
    for (int ks = 0; ks < nks; ++ks) {
        const _Float16* ah = (ks < 2) ? A0h : A1h;
        const _Float16* al = (ks < 2) ? A0l : A1l;
        const int ko = (ks & 1) * 32 + lg * 8;
        h8 fa[4], fl[4];
        #pragma unroll
        for (int mf = 0; mf < 4; ++mf) {
            size_t ad = (size_t)i * 4096 + (mf * 16 + l15) * 64 + ko;
            fa[mf] = *(const h8*)&ah[ad];
            fl[mf] = *(const h8*)&al[ad];
        }
        #pragma unroll
        for (int g = 0; g < 4; ++g) {
            const int gc = g * 64 + h;
            const size_t wd = (size_t)gc * K + ks * 32 + lg * 8;
            const h8 bh = *(const h8*)&Wgh[wd];
            const h8 bl = *(const h8*)&Wgl[wd];
            #pragma unroll
            for (int mf = 0; mf < 4; ++mf) {
                acc0[mf][g] = __builtin_amdgcn_mfma_f32_16x16x32_f16(fa[mf], bh, acc0[mf][g], 0, 0, 0);
                acc1[mf][g] = __builtin_amdgcn_mfma_f32_16x16x32_f16(fa[mf], bl, acc1[mf][g], 0, 0, 0);
                acc1[mf][g] = __builtin_amdgcn_mfma_f32_16x16x32_f16(fl[mf], bh, acc1[mf][g], 0, 0, 0);
            }
        }
    }

    float bs[4], wx0[4], wx1v[4];
    #pragma unroll
    for (int g = 0; g < 4; ++g) {
        int gc = g * 64 + h;
        bs[g] = b1[gc] + b2[gc];
        if (WxE) { wx0[g] = WxE[gc * 2]; wx1v[g] = WxE[gc * 2 + 1]; }
    }

    // C/D: col(gc)=l15-part fixed -> h fixed per lane; row r = i*64 + mf*16 + lg*4 + e
    #pragma unroll
    for (int mf = 0; mf < 4; ++mf) {
        #pragma unroll
        for (int e = 0; e < 4; ++e) {
            const int b = mf * 16 + lg * 4 + e;
            const int r = i * 64 + b;
            float gv[4];
            #pragma unroll
            for (int g = 0; g < 4; ++g)
                gv[g] = acc0[mf][g][e] + acc1[mf][g][e] * (1.f / 2048.f) + bs[g];
            if (AX) {
                float x0 = AX[(size_t)i * 6144 + t * 128 + b * 2 + 0];
                float x1 = AX[(size_t)i * 6144 + t * 128 + b * 2 + 1];
                #pragma unroll
                for (int g = 0; g < 4; ++g)
                    gv[g] = fmaf(x0, wx0[g], fmaf(x1, wx1v[g], gv[g]));
            }
            float ig = 1.f / (1.f + expf(-gv[0]));
            float fg = 1.f / (1.f + expf(-gv[1]));
            float og = 1.f / (1.f + expf(-gv[2]));
            float gg = tanhf(gv[3]);
            size_t cb = (size_t)r * 64 + h;
            float c = fg * Cst[cb] + ig * gg;
            Cst[cb] = c;
            Hout[cb] = og * tanhf(c);
        }
    }
}

// ---------------- final projection ----------------
__global__ __launch_bounds__(256) void proj_kernel(const float* __restrict__ H1,
                                                   const float* __restrict__ Wpj,
                                                   const float* __restrict__ bp,
                                                   float* __restrict__ out)
{
    int r = blockIdx.x * 256 + threadIdx.x;
    if (r >= 64000) return;
    int i = r >> 6, b = r & 63;
    f4 hv[16];
    #pragma unroll
    for (int q = 0; q < 16; ++q) hv[q] = *(const f4*)&H1[(size_t)r * 64 + q * 4];
    #pragma unroll
    for (int hor = 0; hor < 12; ++hor) {
        float s = bp[hor];
        #pragma unroll
        for (int q = 0; q < 16; ++q) {
            f4 w = *(const f4*)&Wpj[hor * 64 + q * 4];
            s = fmaf(hv[q][0], w[0], s);
            s = fmaf(hv[q][1], w[1], s);
            s = fmaf(hv[q][2], w[2], s);
            s = fmaf(hv[q][3], w[3], s);
        }
        out[(size_t)(b * 12 + hor) * 1000 + i] = s;
    }
}

extern "C" void kernel_launch(void* const* d_in, const int* in_sizes, int n_in,
                              void* d_out, int out_size, void* d_ws, size_t ws_size,
                              hipStream_t stream)
{
    const float* x   = (const float*)d_in[0];
    const float* E1  = (const float*)d_in[1];
    const float* E2  = (const float*)d_in[2];
    const float* Wx0 = (const float*)d_in[3];
    const float* bx0 = (const float*)d_in[4];
    const float* Wh0 = (const float*)d_in[5];
    const float* bh0 = (const float*)d_in[6];
    const float* Wx1 = (const float*)d_in[7];
    const float* bx1 = (const float*)d_in[8];
    const float* Wh1 = (const float*)d_in[9];
    const float* bh1 = (const float*)d_in[10];
    const float* Wp  = (const float*)d_in[11];
    const float* bp  = (const float*)d_in[12];
    float* out = (float*)d_out;
    float* ws  = (float*)d_ws;

    float*    AX   = ws + WS_AX;
    _Float16* AH0h = (_Float16*)(ws + WS_AH0H);
    _Float16* AH0l = (_Float16*)(ws + WS_AH0L);
    _Float16* AH1h = (_Float16*)(ws + WS_AH1H);
    _Float16* AH1l = (_Float16*)(ws + WS_AH1L);
    float*    H1F  = ws + WS_H1F;
    float*    C0   = ws + WS_C0;
    float*    C1   = ws + WS_C1;
    _Float16* HTh  = (_Float16*)(ws + WS_HTH);
    _Float16* HTl  = (_Float16*)(ws + WS_HTL);
    _Float16* Ah   = (_Float16*)(ws + WS_AH16);
    _Float16* Al   = (_Float16*)(ws + WS_AL16);
    _Float16* W0h  = (_Float16*)(ws + WS_W0H);
    _Float16* W0l  = (_Float16*)(ws + WS_W0L);
    _Float16* W1h  = (_Float16*)(ws + WS_W1H);
    _Float16* W1l  = (_Float16*)(ws + WS_W1L);
    float*    At   = ws + WS_C0;     // alias: dead before C0 zeroed
    float*    Xr   = ws + WS_AH0H;   // alias: dead before AH0 zeroed
    float*    H0F  = ws + WS_AH1H;   // alias: H0 fp32 between gates0 and gemm_ah #2

    compute_A<<<1000, 256, 0, stream>>>(E1, E2, At);
    transpose_x<<<24000, 256, 0, stream>>>(x, Xr);
    gemm1000<<<dim3(16, 48), 256, 0, stream>>>(At, Xr, AX, 6144);   // AX = A @ Xr
    prep_w2<<<192, 256, 0, stream>>>(Wh0, Wx1, Wh1, W0h, W0l, W1h, W1l);
    prep_A<<<4096, 256, 0, stream>>>(At, Ah, Al);
    zero_kernel<<<8000, 256, 0, stream>>>(ws + WS_C0, 2048000);     // C0,C1 (kills At)
    zero_kernel<<<4096, 256, 0, stream>>>(ws + WS_AH0H, 1048576);   // AH0h/l (kills Xr head)
    zero_kernel<<<4000, 256, 0, stream>>>(H1F, 1024000);            // H1

    for (int t = 0; t < 48; ++t) {
        // layer 0: gates = (A@H0prev) Wh0^T + x-path -> H0 fp32 (in AH1 region), C0
        gates_mfma<<<1000, 256, 0, stream>>>(AH0h, AH0l, nullptr, nullptr,
                                             W0h, W0l, bh0, bx0,
                                             AX, Wx0, t, C0, H0F);
        // AH0 = A @ H0new (split-f16 out; also next step's layer-0 input)
        transpose_split<<<dim3(128, 32), 256, 0, stream>>>(H0F, HTh, HTl);
        gemm_ah<<<dim3(8, 32), 256, 0, stream>>>(Ah, Al, HTh, HTl, AH0h, AH0l);
        // AH1 = A @ H1prev (overwrites H0F alias -- already consumed)
        transpose_split<<<dim3(128, 32), 256, 0, stream>>>(H1F, HTh, HTl);
        gemm_ah<<<dim3(8, 32), 256, 0, stream>>>(Ah, Al, HTh, HTl, AH1h, AH1l);
        // layer 1: gates = (A@H0new) Wx1^T + (A@H1prev) Wh1^T -> H1 fp32, C1
        gates_mfma<<<1000, 256, 0, stream>>>(AH0h, AH0l, AH1h, AH1l,
                                             W1h, W1l, bh1, bx1,
                                             nullptr, nullptr, 0, C1, H1F);
    }
    proj_kernel<<<250, 256, 0, stream>>>(H1F, Wp, bp, out);
    (void)in_sizes; (void)n_in; (void)out_size; (void)ws_size;
}